// Round 3
// baseline (443.502 us; speedup 1.0000x reference)
//
#include <hip/hip_runtime.h>

// Problem constants: N=8, H=32, L=512, S=512, MAX_SPATIAL=100
#define NN 8
#define HH 32
#define LL 512
#define SS 512
#define MAXP 100

// L*S/4 = 65536 float4-units per (n,h) slice
#define LS4 65536

// float4s handled per thread per h-slice (lane-coalesced, 256 apart)
#define VPT 4

typedef float f32x4 __attribute__((ext_vector_type(4)));
typedef int   i32x4 __attribute__((ext_vector_type(4)));

__global__ __launch_bounds__(256) void gpe_kernel(
    const float* __restrict__ QK,
    const int*   __restrict__ pos,
    const float* __restrict__ emb,
    float*       __restrict__ out)
{
    // Table staged transposed: tbl[h*MAXP + p] = emb[p*H + h], row p==0 zeroed.
    __shared__ float tbl[HH * MAXP];
    const int tid = threadIdx.x;
    for (int idx = tid; idx < HH * MAXP; idx += 256) {
        const int p = idx >> 5;          // / HH  (HH == 32)
        const int h = idx & (HH - 1);
        tbl[h * MAXP + p] = (p == 0) ? 0.0f : emb[p * HH + h];
    }
    __syncthreads();

    // Block covers 1024 consecutive float4s (16 KB) of one n-slice per h:
    // 64 blocks per n, 512 blocks total = 2 blocks/CU, 8 waves/CU.
    const int gid  = blockIdx.x;
    const int n    = gid >> 6;                 // 64 blocks per n
    const int ls4_0 = ((gid & 63) << 10) + tid; // base + tid, thread's first float4

    const i32x4* __restrict__ pos4 = (const i32x4*)pos;
    const f32x4* __restrict__ qk4  = (const f32x4*)QK;
    f32x4*       __restrict__ out4 = (f32x4*)out;

    // pos read exactly once; 4 int4 = 16 VGPRs held for the whole kernel
    i32x4 p[VPT];
#pragma unroll
    for (int v = 0; v < VPT; ++v)
        p[v] = pos4[n * LS4 + ls4_0 + v * 256];

    // base index in float4 units; max = 7*32*65536 + 65535 < 2^24
    int idx4 = n * (HH * LS4) + ls4_0;

    // unroll 2 over h x VPT=4 -> 8 independent 1KB loads in flight per wave.
    // nt loads: 268 MB single-use stream, keep it out of L2.
    // normal stores: let L2 absorb/stream write-backs in full-line batches.
#pragma unroll 2
    for (int h = 0; h < HH; ++h, idx4 += LS4) {
        const float* th = &tbl[h * MAXP];
        f32x4 q[VPT];
#pragma unroll
        for (int v = 0; v < VPT; ++v)
            q[v] = __builtin_nontemporal_load(&qk4[idx4 + v * 256]);
#pragma unroll
        for (int v = 0; v < VPT; ++v) {
            q[v].x += th[p[v].x];
            q[v].y += th[p[v].y];
            q[v].z += th[p[v].z];
            q[v].w += th[p[v].w];
        }
#pragma unroll
        for (int v = 0; v < VPT; ++v)
            out4[idx4 + v * 256] = q[v];
    }
}

extern "C" void kernel_launch(void* const* d_in, const int* in_sizes, int n_in,
                              void* d_out, int out_size, void* d_ws, size_t ws_size,
                              hipStream_t stream) {
    const float* QK  = (const float*)d_in[0];
    const int*   pos = (const int*)d_in[1];
    const float* emb = (const float*)d_in[2];
    float*       out = (float*)d_out;

    // N*L*S/4 float4s / (256 threads * VPT) = 512 blocks
    const int total_vec = (NN * LL * SS) / 4;
    const int block = 256;
    const int grid  = total_vec / (block * VPT);
    gpe_kernel<<<grid, block, 0, stream>>>(QK, pos, emb, out);
}